// Round 10
// baseline (426.789 us; speedup 1.0000x reference)
//
#include <hip/hip_runtime.h>
#include <cstdint>
#include <cstddef>

#define NEG_SLOPE 0.2f
#define EPS_BN 1e-5f

typedef __bf16 bf16x8 __attribute__((ext_vector_type(8)));
typedef float  f32x4  __attribute__((ext_vector_type(4)));
typedef float  f32x2  __attribute__((ext_vector_type(2)));
typedef unsigned short ushort_t;

static __device__ __forceinline__ float lrelu(float x){ return x > 0.f ? x : NEG_SLOPE * x; }
static __device__ __forceinline__ float elu(float x){ return x > 0.f ? x : __expf(x) - 1.f; }

static __device__ __forceinline__ ushort_t f2bf(float f){
  unsigned u = __float_as_uint(f);
  u += 0x7fffu + ((u >> 16) & 1u);        // RNE (inputs finite)
  return (ushort_t)(u >> 16);
}
static __device__ __forceinline__ void unpk(unsigned u, float& lo, float& hi){
  lo = __uint_as_float(u << 16);
  hi = __uint_as_float(u & 0xffff0000u);
}
static __device__ __forceinline__ f32x2 unpk2(unsigned u){
  f32x2 r;
  r.x = __uint_as_float(u << 16);
  r.y = __uint_as_float(u & 0xffff0000u);
  return r;
}

union BF8 { bf16x8 v; ushort_t u[8]; };

static inline int ceil_div(int a, int b){ return (a + b - 1) / b; }

// ---------------- weight repack to MFMA B-fragment layout ----------------

static __device__ void packW_body(const float* W, ushort_t* Wp, int K, int Nn, int idx){
  int lane = idx & 63;
  int rest = idx >> 6;
  int KS = K >> 5;
  int s = rest % KS, t = rest / KS;
  int n  = t * 16 + (lane & 15);
  int k0 = s * 32 + (lane >> 4) * 8;
  ushort_t tmp[8];
  #pragma unroll
  for(int j = 0; j < 8; j++) tmp[j] = f2bf(W[(size_t)(k0 + j) * Nn + n]);
  uint4 pk;
  pk.x = tmp[0] | ((unsigned)tmp[1] << 16);
  pk.y = tmp[2] | ((unsigned)tmp[3] << 16);
  pk.z = tmp[4] | ((unsigned)tmp[5] << 16);
  pk.w = tmp[6] | ((unsigned)tmp[7] << 16);
  *reinterpret_cast<uint4*>(Wp + (size_t)idx * 8) = pk;
}

// init: blocks [0,28) pack all 3 weights; remaining blocks zero meta+deg8 (contiguous).
__global__ void init_kernel(unsigned* __restrict__ zbase, int ztotal,
                            const float* __restrict__ W1, const float* __restrict__ W2,
                            const float* __restrict__ W3, ushort_t* __restrict__ W1p,
                            ushort_t* __restrict__ W2p, ushort_t* __restrict__ W3p){
  int b = blockIdx.x;
  if(b < 28){
    int idx = b * 256 + threadIdx.x;
    if(idx < 4096)       packW_body(W1, W1p, 128, 256, idx);
    else if(idx < 6144)  packW_body(W2, W2p, 256, 64,  idx - 4096);
    else if(idx < 7168)  packW_body(W3, W3p, 64,  128, idx - 6144);
  } else {
    int i = (b - 28) * 256 + threadIdx.x;
    if(i < ztotal) zbase[i] = 0u;
  }
}

// ---------------- unified MFMA GEMM body ----------------
// AMODE 0: A fp32, convert in-register. AMODE 1: A bf16 with fused BN(scale,shift)+ELU.
// Block = 4 waves, 64 rows; block covers ALL NT col-tiles, A read once.
// H>0: fused alpha epilogue.

template<int K, int NT, int AMODE, int H>
static __device__ __forceinline__ void gemm_body(int bx, const void* __restrict__ Asrc,
                                                 const ushort_t* __restrict__ Bp,
                                                 ushort_t* __restrict__ C, int M,
                                                 const float* __restrict__ scale,
                                                 const float* __restrict__ shift,
                                                 const float* __restrict__ a_src,
                                                 const float* __restrict__ a_dst,
                                                 float* __restrict__ as_,
                                                 float* __restrict__ ad_){
  constexpr int KS = K >> 5;
  int lane = threadIdx.x & 63, wv = threadIdx.x >> 6;
  int row0 = bx * 64 + wv * 16;
  int mi = lane & 15, q = lane >> 4;
  int arow = row0 + mi; if(arow > M - 1) arow = M - 1;   // clamp: loads safe, stores guarded
  const bf16x8* bbase = reinterpret_cast<const bf16x8*>(Bp) + lane;
  f32x4 acc[NT] = {};
  #pragma unroll
  for(int s = 0; s < KS; s++){
    BF8 cv;
    if(AMODE == 0){
      const float* ap = (const float*)Asrc + (size_t)arow * K + s * 32 + q * 8;
      float4 u0 = *reinterpret_cast<const float4*>(ap);
      float4 u1 = *reinterpret_cast<const float4*>(ap + 4);
      cv.u[0] = f2bf(u0.x); cv.u[1] = f2bf(u0.y); cv.u[2] = f2bf(u0.z); cv.u[3] = f2bf(u0.w);
      cv.u[4] = f2bf(u1.x); cv.u[5] = f2bf(u1.y); cv.u[6] = f2bf(u1.z); cv.u[7] = f2bf(u1.w);
    } else {
      const ushort_t* ap = (const ushort_t*)Asrc + (size_t)arow * K + s * 32 + q * 8;
      uint4 u = *reinterpret_cast<const uint4*>(ap);
      int c0 = s * 32 + q * 8;
      float4 sc0 = *reinterpret_cast<const float4*>(scale + c0);
      float4 sc1 = *reinterpret_cast<const float4*>(scale + c0 + 4);
      float4 sh0 = *reinterpret_cast<const float4*>(shift + c0);
      float4 sh1 = *reinterpret_cast<const float4*>(shift + c0 + 4);
      float a, b;
      unpk(u.x, a, b); cv.u[0] = f2bf(elu(a * sc0.x + sh0.x)); cv.u[1] = f2bf(elu(b * sc0.y + sh0.y));
      unpk(u.y, a, b); cv.u[2] = f2bf(elu(a * sc0.z + sh0.z)); cv.u[3] = f2bf(elu(b * sc0.w + sh0.w));
      unpk(u.z, a, b); cv.u[4] = f2bf(elu(a * sc1.x + sh1.x)); cv.u[5] = f2bf(elu(b * sc1.y + sh1.y));
      unpk(u.w, a, b); cv.u[6] = f2bf(elu(a * sc1.z + sh1.z)); cv.u[7] = f2bf(elu(b * sc1.w + sh1.w));
    }
    bf16x8 af = cv.v;
    #pragma unroll
    for(int t = 0; t < NT; t++){
      bf16x8 bfr = bbase[((size_t)t * KS + s) * 64];
      acc[t] = __builtin_amdgcn_mfma_f32_16x16x32_bf16(af, bfr, acc[t], 0, 0, 0);
    }
  }
  #pragma unroll
  for(int t = 0; t < NT; t++){
    #pragma unroll
    for(int r = 0; r < 4; r++){
      int gr = row0 + q * 4 + r;
      if(gr < M) C[(size_t)gr * (NT * 16) + t * 16 + mi] = f2bf(acc[t][r]);
    }
  }
  if(H > 0){
    #pragma unroll
    for(int hh = 0; hh < H; hh++){
      #pragma unroll
      for(int r = 0; r < 4; r++){
        float ps = 0.f, pd = 0.f;
        #pragma unroll
        for(int tt = 0; tt < 4; tt++){
          int t = hh * 4 + tt;
          float av = acc[t][r];
          int c = t * 16 + mi;
          ps += av * a_src[c];
          pd += av * a_dst[c];
        }
        #pragma unroll
        for(int off = 1; off < 16; off <<= 1){
          ps += __shfl_xor(ps, off);
          pd += __shfl_xor(pd, off);
        }
        int gr = row0 + q * 4 + r;
        if(mi == 0 && gr < M){
          as_[(size_t)gr * H + hh] = ps;
          ad_[(size_t)gr * H + hh] = pd;
        }
      }
    }
  }
}

template<int K, int NT, int AMODE, int H>
__global__ __launch_bounds__(256) void gemm_kernel(const void* __restrict__ Asrc,
                                                   const ushort_t* __restrict__ Bp,
                                                   ushort_t* __restrict__ C, int M,
                                                   const float* __restrict__ scale,
                                                   const float* __restrict__ shift,
                                                   const float* __restrict__ a_src,
                                                   const float* __restrict__ a_dst,
                                                   float* __restrict__ as_,
                                                   float* __restrict__ ad_){
  gemm_body<K, NT, AMODE, H>(blockIdx.x, Asrc, Bp, C, M, scale, shift, a_src, a_dst, as_, ad_);
}

// role-split launch: blocks [0,GB) = GEMM1, blocks [GB,..) = degree histogram.
// Replica index MUST be derived from (b - GB) so it matches scatter's (e/256)&7
// partition exactly (same edge -> same replica); XCD locality is a bonus, not a
// correctness requirement.
__global__ __launch_bounds__(256) void hist_gemm1_kernel(int GB, const int* __restrict__ ei,
                                                         int* __restrict__ deg8, int E, int N,
                                                         const float* __restrict__ x,
                                                         const ushort_t* __restrict__ W1p,
                                                         ushort_t* __restrict__ h1b,
                                                         const float* __restrict__ a1s,
                                                         const float* __restrict__ a1d,
                                                         float* __restrict__ as_,
                                                         float* __restrict__ ad_){
  int b = blockIdx.x;
  if(b < GB){
    gemm_body<128, 16, 0, 4>(b, x, W1p, h1b, N, nullptr, nullptr, a1s, a1d, as_, ad_);
  } else {
    int hb = b - GB;
    int e = hb * 256 + threadIdx.x;
    if(e < E + N){
      int d = (e < E) ? ei[E + e] : (e - E);   // self loop for e >= E
      atomicAdd(&deg8[(size_t)(hb & 7) * N + d], 1);
    }
  }
}

// ---------------- CSR scan over 8 replicas ----------------
// Reads deg8[r][i], writes per-replica cursors back IN PLACE (deg8 becomes cur8),
// rowptr[i] = block-local INCLUSIVE prefix of node totals; last block scans partials.

__global__ __launch_bounds__(256) void scan1_kernel(int* __restrict__ deg8, int* __restrict__ rowptr,
                                                    int* __restrict__ partials,
                                                    unsigned* __restrict__ tick, int n){
  int t = threadIdx.x, lane = t & 63, wv = t >> 6;
  int base = blockIdx.x * 2048 + t * 8;
  int v[8]; int run = 0;
  #pragma unroll
  for(int k = 0; k < 8; k++){
    int i = base + k; int s = 0;
    if(i < n){
      #pragma unroll
      for(int r = 0; r < 8; r++) s += deg8[(size_t)r * n + i];
    }
    v[k] = s; run += s;
  }
  int sc = run;
  #pragma unroll
  for(int off = 1; off < 64; off <<= 1){
    int u = __shfl_up(sc, off);
    if(lane >= off) sc += u;
  }
  __shared__ int wtot[4], woff[4];
  __shared__ bool slast;
  if(lane == 63) wtot[wv] = sc;
  __syncthreads();
  if(t == 0){
    int a = 0;
    #pragma unroll
    for(int i = 0; i < 4; i++){ woff[i] = a; a += wtot[i]; }
    partials[blockIdx.x] = a;
  }
  __syncthreads();
  int excl = (sc - run) + woff[wv];
  #pragma unroll
  for(int k = 0; k < 8; k++){
    int i = base + k;
    if(i < n){
      int run2 = excl;
      #pragma unroll
      for(int r = 0; r < 8; r++){
        int tmp = deg8[(size_t)r * n + i];
        deg8[(size_t)r * n + i] = run2;      // replica-r cursor (block-local)
        run2 += tmp;
      }
      excl = run2;
      rowptr[i] = excl;                      // inclusive local prefix (segment end)
    }
  }
  if(t == 0){
    __threadfence();
    slast = (atomicAdd(tick, 1u) == (unsigned)(gridDim.x - 1));
  }
  __syncthreads();
  if(slast && t < 64){
    int nb = gridDim.x;
    int pv = (t < nb) ? atomicAdd(&partials[t], 0) : 0;   // coherent read
    int psc = pv;
    #pragma unroll
    for(int off = 1; off < 64; off <<= 1){
      int u = __shfl_up(psc, off);
      if(t >= off) psc += u;
    }
    if(t < nb) partials[t] = psc - pv;
  }
}

// scatter bumps cur8[blockIdx&7][d]; same (e/256)&7 replica partition as hist.
__global__ void scatter_kernel(const int* __restrict__ ei, int* __restrict__ cur8,
                               const int* __restrict__ part, int* __restrict__ col, int E, int N){
  int e = blockIdx.x * 256 + threadIdx.x;
  if(e >= E + N) return;
  int s, d;
  if(e < E){ s = ei[e]; d = ei[E + e]; } else { s = e - E; d = e - E; }
  int pos = atomicAdd(&cur8[(size_t)(blockIdx.x & 7) * N + d], 1) + part[d >> 11];
  col[pos] = s;
}

// ---------------- single-pass GAT aggregation (round-5 loop, packed-f32 accumulate) ----------------
// out = (sum w*h)/(sum w); logits tiny so no max-subtraction needed.
// H=4: 2 lane-groups of 32; 4 edges in flight via 4x unroll; no LDS, no atomics.

__global__ __launch_bounds__(256) void gat_agg4_kernel(const ushort_t* __restrict__ hfeat,
                                                       const float* __restrict__ as_,
                                                       const float* __restrict__ ad_,
                                                       const int* __restrict__ rowptr,
                                                       const int* __restrict__ part,
                                                       const int* __restrict__ col,
                                                       const float* __restrict__ bias,
                                                       ushort_t* __restrict__ out, int N){
  int wid = threadIdx.x >> 6, lane = threadIdx.x & 63;
  int n = blockIdx.x * 4 + wid;
  if(n > N - 1) n = N - 1;
  int start = n ? rowptr[n - 1] + part[(n - 1) >> 11] : 0;
  int end   = rowptr[n] + part[n >> 11];
  int g = lane >> 5, l = lane & 31, hidx = l >> 3;
  float adh = ad_[(size_t)n * 4 + hidx];
  float den = 0.f;
  f32x2 acc2[4] = {};
  auto body = [&](int j){
    int s = col[j];
    float w = __expf(lrelu(as_[(size_t)s * 4 + hidx] + adh));
    uint4 u = *reinterpret_cast<const uint4*>(hfeat + (size_t)s * 256 + 8 * l);
    den += w;
    acc2[0] += unpk2(u.x) * w;
    acc2[1] += unpk2(u.y) * w;
    acc2[2] += unpk2(u.z) * w;
    acc2[3] += unpk2(u.w) * w;
  };
  int j = start + g;
  for(; j + 6 < end; j += 8){ body(j); body(j + 2); body(j + 4); body(j + 6); }
  for(; j < end; j += 2) body(j);
  den += __shfl_xor(den, 32);
  #pragma unroll
  for(int k = 0; k < 4; k++){
    acc2[k].x += __shfl_xor(acc2[k].x, 32);
    acc2[k].y += __shfl_xor(acc2[k].y, 32);
  }
  float dinv = 1.f / (den + 1e-16f);
  int cbase = 8 * l + g * 4;
  f32x2 p0 = g ? acc2[2] : acc2[0];
  f32x2 p1 = g ? acc2[3] : acc2[1];
  ushort_t o0 = f2bf(p0.x * dinv + bias[cbase + 0]);
  ushort_t o1 = f2bf(p0.y * dinv + bias[cbase + 1]);
  ushort_t o2 = f2bf(p1.x * dinv + bias[cbase + 2]);
  ushort_t o3 = f2bf(p1.y * dinv + bias[cbase + 3]);
  uint2 pk; pk.x = o0 | ((unsigned)o1 << 16); pk.y = o2 | ((unsigned)o3 << 16);
  *reinterpret_cast<uint2*>(out + (size_t)n * 256 + cbase) = pk;
}

// H=1: 4 lane-groups of 16, uint2 gathers, round-5 loop, packed accumulate.

__global__ __launch_bounds__(256) void gat_agg1_kernel(const ushort_t* __restrict__ hfeat,
                                                       const float* __restrict__ as_,
                                                       const float* __restrict__ ad_,
                                                       const int* __restrict__ rowptr,
                                                       const int* __restrict__ part,
                                                       const int* __restrict__ col,
                                                       const float* __restrict__ bias,
                                                       ushort_t* __restrict__ out, int N){
  int wid = threadIdx.x >> 6, lane = threadIdx.x & 63;
  int n = blockIdx.x * 4 + wid;
  if(n > N - 1) n = N - 1;
  int start = n ? rowptr[n - 1] + part[(n - 1) >> 11] : 0;
  int end   = rowptr[n] + part[n >> 11];
  int g = lane >> 4, l = lane & 15;
  float adn = ad_[n];
  float den = 0.f;
  f32x2 acc2[2] = {};
  auto body = [&](int j){
    int s = col[j];
    float w = __expf(lrelu(as_[s] + adn));
    uint2 u = *reinterpret_cast<const uint2*>(hfeat + (size_t)s * 64 + 4 * l);
    den += w;
    acc2[0] += unpk2(u.x) * w;
    acc2[1] += unpk2(u.y) * w;
  };
  int j = start + g;
  for(; j + 4 < end; j += 8){ body(j); body(j + 4); }
  if(j < end) body(j);
  den += __shfl_xor(den, 16); den += __shfl_xor(den, 32);
  #pragma unroll
  for(int k = 0; k < 2; k++){
    acc2[k].x += __shfl_xor(acc2[k].x, 16); acc2[k].x += __shfl_xor(acc2[k].x, 32);
    acc2[k].y += __shfl_xor(acc2[k].y, 16); acc2[k].y += __shfl_xor(acc2[k].y, 32);
  }
  float dinv = 1.f / (den + 1e-16f);
  if(g == 0){
    ushort_t o0 = f2bf(acc2[0].x * dinv + bias[4 * l + 0]);
    ushort_t o1 = f2bf(acc2[0].y * dinv + bias[4 * l + 1]);
    ushort_t o2 = f2bf(acc2[1].x * dinv + bias[4 * l + 2]);
    ushort_t o3 = f2bf(acc2[1].y * dinv + bias[4 * l + 3]);
    uint2 pk; pk.x = o0 | ((unsigned)o1 << 16); pk.y = o2 | ((unsigned)o3 << 16);
    *reinterpret_cast<uint2*>(out + (size_t)n * 64 + 4 * l) = pk;
  }
}

// ---------------- column stats (vectorized uint4 = 8ch/thread) + last-block finalize ----------------
// 512 blocks only: grid-level atomic reduction stays cheap.

template<int C>
__global__ __launch_bounds__(256) void colstats_fin_kernel(const ushort_t* __restrict__ x, int N,
                                                           float* __restrict__ stats,
                                                           const float* __restrict__ gamma,
                                                           const float* __restrict__ beta,
                                                           float* __restrict__ scale,
                                                           float* __restrict__ shift,
                                                           unsigned* __restrict__ ticket, int nblk){
  constexpr int TPR = C / 8;           // threads per row
  constexpr int RPB = 256 / TPR;       // rows per block-iter
  int t = threadIdx.x;
  int c0 = (t % TPR) * 8, rg = t / TPR;
  float sum[8] = {}, sq[8] = {};
  for(int r = blockIdx.x * RPB + rg; r < N; r += gridDim.x * RPB){
    uint4 u = *reinterpret_cast<const uint4*>(x + (size_t)r * C + c0);
    float a, b;
    unpk(u.x, a, b); sum[0] += a; sq[0] += a * a; sum[1] += b; sq[1] += b * b;
    unpk(u.y, a, b); sum[2] += a; sq[2] += a * a; sum[3] += b; sq[3] += b * b;
    unpk(u.z, a, b); sum[4] += a; sq[4] += a * a; sum[5] += b; sq[5] += b * b;
    unpk(u.w, a, b); sum[6] += a; sq[6] += a * a; sum[7] += b; sq[7] += b * b;
  }
  __shared__ float red[2][256][8];     // 16 KB
  #pragma unroll
  for(int k = 0; k < 8; k++){ red[0][t][k] = sum[k]; red[1][t][k] = sq[k]; }
  __syncthreads();
  if(t < C){
    int tr = t >> 3, k = t & 7;
    float S = 0.f, Q = 0.f;
    for(int g2 = 0; g2 < RPB; g2++){
      S += red[0][g2 * TPR + tr][k];
      Q += red[1][g2 * TPR + tr][k];
    }
    atomicAdd(&stats[t], S);
    atomicAdd(&stats[C + t], Q);
  }
  __shared__ bool is_last;
  __syncthreads();
  if(t == 0){
    __threadfence();
    is_last = (atomicAdd(ticket, 1u) == (unsigned)(nblk - 1));
  }
  __syncthreads();
  if(is_last && t < C){
    float S = atomicAdd(&stats[t], 0.f);        // coherent read
    float Q = atomicAdd(&stats[C + t], 0.f);
    float invN = 1.f / (float)N;
    float mu = S * invN;
    float var = Q * invN - mu * mu;
    float rs = rsqrtf(var + EPS_BN);
    float scl = rs * gamma[t];
    scale[t] = scl;
    shift[t] = beta[t] - mu * scl;
  }
}

// ---------------- final BN (pure affine, vectorized 8ch/thread, fp32 out) ----------------

__global__ void bn3_kernel(const ushort_t* __restrict__ x, const float* __restrict__ scale,
                           const float* __restrict__ shift, float* __restrict__ y, long total8){
  long i = (long)blockIdx.x * 256 + threadIdx.x;
  if(i >= total8) return;
  long e0 = i * 8;
  int c0 = (int)(e0 & 127);
  uint4 u = *reinterpret_cast<const uint4*>(x + e0);
  float4 sc0 = *reinterpret_cast<const float4*>(scale + c0);
  float4 sc1 = *reinterpret_cast<const float4*>(scale + c0 + 4);
  float4 sh0 = *reinterpret_cast<const float4*>(shift + c0);
  float4 sh1 = *reinterpret_cast<const float4*>(shift + c0 + 4);
  float a, b;
  float4 o0, o1;
  unpk(u.x, a, b); o0.x = a * sc0.x + sh0.x; o0.y = b * sc0.y + sh0.y;
  unpk(u.y, a, b); o0.z = a * sc0.z + sh0.z; o0.w = b * sc0.w + sh0.w;
  unpk(u.z, a, b); o1.x = a * sc1.x + sh1.x; o1.y = b * sc1.y + sh1.y;
  unpk(u.w, a, b); o1.z = a * sc1.z + sh1.z; o1.w = b * sc1.w + sh1.w;
  *reinterpret_cast<float4*>(y + e0) = o0;
  *reinterpret_cast<float4*>(y + e0 + 4) = o1;
}

// ---------------- launch ----------------

extern "C" void kernel_launch(void* const* d_in, const int* in_sizes, int n_in,
                              void* d_out, int out_size, void* d_ws, size_t ws_size,
                              hipStream_t stream){
  const float* x   = (const float*)d_in[0];
  const int*   ei  = (const int*)  d_in[1];
  const float* W1  = (const float*)d_in[2];
  const float* a1s = (const float*)d_in[3];
  const float* a1d = (const float*)d_in[4];
  const float* b1  = (const float*)d_in[5];
  const float* W2  = (const float*)d_in[6];
  const float* a2s = (const float*)d_in[7];
  const float* a2d = (const float*)d_in[8];
  const float* b2  = (const float*)d_in[9];
  const float* Wp  = (const float*)d_in[10];
  const float* g1  = (const float*)d_in[12]; const float* be1 = (const float*)d_in[13];
  const float* g2  = (const float*)d_in[14]; const float* be2 = (const float*)d_in[15];
  const float* g3  = (const float*)d_in[16]; const float* be3 = (const float*)d_in[17];
  float* out = (float*)d_out;

  const int N  = in_sizes[0] / 128;
  const int E  = in_sizes[1] / 2;
  const int EP = E + N;
  const int Mpad = ((N + 63) / 64) * 64;
  const int NB = ceil_div(N, 2048);
  const int GB = Mpad / 64;
  const int HB = ceil_div(EP, 256);

  // ---- workspace carve ----
  char* p = (char*)d_ws;
  auto carve = [&](size_t bytes) -> char* {
    char* r = p; p += (bytes + 255) & ~(size_t)255; return r;
  };
  float* meta   = (float*)carve(2048 * 4);          // stats/scale/shift/tickets (zeroed)
  int*   deg8   = (int*)carve((size_t)8 * N * 4);   // contiguous after meta; becomes cur8
  int*   rowptr = (int*)carve((size_t)(N + 1) * 4);
  int*   col    = (int*)carve((size_t)EP * 4);
  int*   part   = (int*)carve(64 * 4);
  float* as_    = (float*)carve((size_t)N * 4 * 4);
  float* ad_    = (float*)carve((size_t)N * 4 * 4);
  ushort_t* W1p = (ushort_t*)carve((size_t)128 * 256 * 2);
  ushort_t* W2p = (ushort_t*)carve((size_t)256 * 64 * 2);
  ushort_t* W3p = (ushort_t*)carve((size_t)64 * 128 * 2);
  ushort_t* h1b   = (ushort_t*)carve((size_t)Mpad * 256 * 2);
  ushort_t* out1b = (ushort_t*)carve((size_t)Mpad * 256 * 2);
  ushort_t* h2b   = (ushort_t*)carve((size_t)Mpad * 64 * 2);
  ushort_t* out2b = (ushort_t*)carve((size_t)Mpad * 64 * 2);
  ushort_t* h3b   = (ushort_t*)carve((size_t)Mpad * 128 * 2);

  float* stats1 = meta;        float* scale1 = meta + 512;  float* shift1 = meta + 768;
  float* stats2 = meta + 1024; float* scale2 = meta + 1152; float* shift2 = meta + 1216;
  float* stats3 = meta + 1280; float* scale3 = meta + 1536; float* shift3 = meta + 1664;
  unsigned* tick = (unsigned*)(meta + 1792);        // [0..2]=colstats, [3]=scan

  const int ZT = 2048 + 8 * N;
  // 1) zero meta+deg8 + pack all weights (role-split)
  init_kernel<<<28 + ceil_div(ZT, 256), 256, 0, stream>>>((unsigned*)meta, ZT,
                                                          W1, W2, Wp, W1p, W2p, W3p);
  // 2) GEMM1 (fp32 A, fused f2bf + alpha) + replicated degree histogram (role-split)
  hist_gemm1_kernel<<<GB + HB, 256, 0, stream>>>(GB, ei, deg8, E, N, x, W1p, h1b, a1s, a1d, as_, ad_);
  // 3) CSR scan (8-replica sum; deg8 -> cur8 in place; rowptr inclusive-local)
  scan1_kernel<<<NB, 256, 0, stream>>>(deg8, rowptr, part, tick + 3, N);
  // 4) scatter (replica-partitioned atomics)
  scatter_kernel<<<HB, 256, 0, stream>>>(ei, deg8, part, col, E, N);
  // 5) layer-1 aggregation
  gat_agg4_kernel<<<ceil_div(N, 4), 256, 0, stream>>>(h1b, as_, ad_, rowptr, part, col, b1, out1b, N);
  colstats_fin_kernel<256><<<512, 256, 0, stream>>>(out1b, N, stats1, g1, be1, scale1, shift1, tick + 0, 512);
  // 6) GEMM2 (fused BN1+ELU on A + alpha)
  gemm_kernel<256, 4, 1, 1><<<GB, 256, 0, stream>>>(out1b, W2p, h2b, N, scale1, shift1, a2s, a2d, as_, ad_);
  // 7) layer-2 aggregation
  gat_agg1_kernel<<<ceil_div(N, 4), 256, 0, stream>>>(h2b, as_, ad_, rowptr, part, col, b2, out2b, N);
  colstats_fin_kernel<64><<<512, 256, 0, stream>>>(out2b, N, stats2, g2, be2, scale2, shift2, tick + 1, 512);
  // 8) projection GEMM (fused BN2+ELU on A)
  gemm_kernel<64, 8, 1, 0><<<GB, 256, 0, stream>>>(out2b, W3p, h3b, N, scale2, shift2, nullptr, nullptr, nullptr, nullptr);
  colstats_fin_kernel<128><<<512, 256, 0, stream>>>(h3b, N, stats3, g3, be3, scale3, shift3, tick + 2, 512);
  // 9) final BN
  bn3_kernel<<<ceil_div(N * 16, 256), 256, 0, stream>>>(h3b, scale3, shift3, out, (long)N * 16);
}

// Round 11
// 413.377 us; speedup vs baseline: 1.0324x; 1.0324x over previous
//
#include <hip/hip_runtime.h>
#include <cstdint>
#include <cstddef>

#define NEG_SLOPE 0.2f
#define EPS_BN 1e-5f

typedef __bf16 bf16x8 __attribute__((ext_vector_type(8)));
typedef float  f32x4  __attribute__((ext_vector_type(4)));
typedef float  f32x2  __attribute__((ext_vector_type(2)));
typedef unsigned short ushort_t;

static __device__ __forceinline__ float lrelu(float x){ return x > 0.f ? x : NEG_SLOPE * x; }
static __device__ __forceinline__ float elu(float x){ return x > 0.f ? x : __expf(x) - 1.f; }

static __device__ __forceinline__ ushort_t f2bf(float f){
  unsigned u = __float_as_uint(f);
  u += 0x7fffu + ((u >> 16) & 1u);        // RNE (inputs finite)
  return (ushort_t)(u >> 16);
}
static __device__ __forceinline__ void unpk(unsigned u, float& lo, float& hi){
  lo = __uint_as_float(u << 16);
  hi = __uint_as_float(u & 0xffff0000u);
}
static __device__ __forceinline__ f32x2 unpk2(unsigned u){
  f32x2 r;
  r.x = __uint_as_float(u << 16);
  r.y = __uint_as_float(u & 0xffff0000u);
  return r;
}

union BF8 { bf16x8 v; ushort_t u[8]; };

static inline int ceil_div(int a, int b){ return (a + b - 1) / b; }

// ---------------- weight repack to MFMA B-fragment layout ----------------

static __device__ void packW_body(const float* W, ushort_t* Wp, int K, int Nn, int idx){
  int lane = idx & 63;
  int rest = idx >> 6;
  int KS = K >> 5;
  int s = rest % KS, t = rest / KS;
  int n  = t * 16 + (lane & 15);
  int k0 = s * 32 + (lane >> 4) * 8;
  ushort_t tmp[8];
  #pragma unroll
  for(int j = 0; j < 8; j++) tmp[j] = f2bf(W[(size_t)(k0 + j) * Nn + n]);
  uint4 pk;
  pk.x = tmp[0] | ((unsigned)tmp[1] << 16);
  pk.y = tmp[2] | ((unsigned)tmp[3] << 16);
  pk.z = tmp[4] | ((unsigned)tmp[5] << 16);
  pk.w = tmp[6] | ((unsigned)tmp[7] << 16);
  *reinterpret_cast<uint4*>(Wp + (size_t)idx * 8) = pk;
}

// init: blocks [0,28) pack all 3 weights; remaining blocks zero meta+deg8 (contiguous).
__global__ void init_kernel(unsigned* __restrict__ zbase, int ztotal,
                            const float* __restrict__ W1, const float* __restrict__ W2,
                            const float* __restrict__ W3, ushort_t* __restrict__ W1p,
                            ushort_t* __restrict__ W2p, ushort_t* __restrict__ W3p){
  int b = blockIdx.x;
  if(b < 28){
    int idx = b * 256 + threadIdx.x;
    if(idx < 4096)       packW_body(W1, W1p, 128, 256, idx);
    else if(idx < 6144)  packW_body(W2, W2p, 256, 64,  idx - 4096);
    else if(idx < 7168)  packW_body(W3, W3p, 64,  128, idx - 6144);
  } else {
    int i = (b - 28) * 256 + threadIdx.x;
    if(i < ztotal) zbase[i] = 0u;
  }
}

// ---------------- unified MFMA GEMM body ----------------
// AMODE 0: A fp32, convert in-register. AMODE 1: A bf16 with fused BN(scale,shift)+ELU.
// Block = 4 waves, 64 rows; covers NT col-tiles starting at tile index colt.
// C row stride = Ntot elements. ALPHA>0: fused alpha dot-products for head `head`
// (a_src/a_dst indexed by global column (colt+t)*16+mi; output as_[row*ALPHA+head]).

template<int K, int NT, int AMODE, int ALPHA>
static __device__ __forceinline__ void gemm_body(int bx, int colt, int Ntot, int head,
                                                 const void* __restrict__ Asrc,
                                                 const ushort_t* __restrict__ Bp,
                                                 ushort_t* __restrict__ C, int M,
                                                 const float* __restrict__ scale,
                                                 const float* __restrict__ shift,
                                                 const float* __restrict__ a_src,
                                                 const float* __restrict__ a_dst,
                                                 float* __restrict__ as_,
                                                 float* __restrict__ ad_){
  constexpr int KS = K >> 5;
  int lane = threadIdx.x & 63, wv = threadIdx.x >> 6;
  int row0 = bx * 64 + wv * 16;
  int mi = lane & 15, q = lane >> 4;
  int arow = row0 + mi; if(arow > M - 1) arow = M - 1;   // clamp: loads safe, stores guarded
  const bf16x8* bbase = reinterpret_cast<const bf16x8*>(Bp) + lane;
  f32x4 acc[NT] = {};
  #pragma unroll
  for(int s = 0; s < KS; s++){
    BF8 cv;
    if(AMODE == 0){
      const float* ap = (const float*)Asrc + (size_t)arow * K + s * 32 + q * 8;
      float4 u0 = *reinterpret_cast<const float4*>(ap);
      float4 u1 = *reinterpret_cast<const float4*>(ap + 4);
      cv.u[0] = f2bf(u0.x); cv.u[1] = f2bf(u0.y); cv.u[2] = f2bf(u0.z); cv.u[3] = f2bf(u0.w);
      cv.u[4] = f2bf(u1.x); cv.u[5] = f2bf(u1.y); cv.u[6] = f2bf(u1.z); cv.u[7] = f2bf(u1.w);
    } else {
      const ushort_t* ap = (const ushort_t*)Asrc + (size_t)arow * K + s * 32 + q * 8;
      uint4 u = *reinterpret_cast<const uint4*>(ap);
      int c0 = s * 32 + q * 8;
      float4 sc0 = *reinterpret_cast<const float4*>(scale + c0);
      float4 sc1 = *reinterpret_cast<const float4*>(scale + c0 + 4);
      float4 sh0 = *reinterpret_cast<const float4*>(shift + c0);
      float4 sh1 = *reinterpret_cast<const float4*>(shift + c0 + 4);
      float a, b;
      unpk(u.x, a, b); cv.u[0] = f2bf(elu(a * sc0.x + sh0.x)); cv.u[1] = f2bf(elu(b * sc0.y + sh0.y));
      unpk(u.y, a, b); cv.u[2] = f2bf(elu(a * sc0.z + sh0.z)); cv.u[3] = f2bf(elu(b * sc0.w + sh0.w));
      unpk(u.z, a, b); cv.u[4] = f2bf(elu(a * sc1.x + sh1.x)); cv.u[5] = f2bf(elu(b * sc1.y + sh1.y));
      unpk(u.w, a, b); cv.u[6] = f2bf(elu(a * sc1.z + sh1.z)); cv.u[7] = f2bf(elu(b * sc1.w + sh1.w));
    }
    bf16x8 af = cv.v;
    #pragma unroll
    for(int t = 0; t < NT; t++){
      bf16x8 bfr = bbase[((size_t)(colt + t) * KS + s) * 64];
      acc[t] = __builtin_amdgcn_mfma_f32_16x16x32_bf16(af, bfr, acc[t], 0, 0, 0);
    }
  }
  #pragma unroll
  for(int t = 0; t < NT; t++){
    #pragma unroll
    for(int r = 0; r < 4; r++){
      int gr = row0 + q * 4 + r;
      if(gr < M) C[(size_t)gr * Ntot + (colt + t) * 16 + mi] = f2bf(acc[t][r]);
    }
  }
  if(ALPHA > 0){
    #pragma unroll
    for(int r = 0; r < 4; r++){
      float ps = 0.f, pd = 0.f;
      #pragma unroll
      for(int t = 0; t < NT; t++){
        float av = acc[t][r];
        int c = (colt + t) * 16 + mi;
        ps += av * a_src[c];
        pd += av * a_dst[c];
      }
      #pragma unroll
      for(int off = 1; off < 16; off <<= 1){
        ps += __shfl_xor(ps, off);
        pd += __shfl_xor(pd, off);
      }
      int gr = row0 + q * 4 + r;
      if(mi == 0 && gr < M){
        as_[(size_t)gr * ALPHA + head] = ps;
        ad_[(size_t)gr * ALPHA + head] = pd;
      }
    }
  }
}

template<int K, int NT, int AMODE, int ALPHA>
__global__ __launch_bounds__(256) void gemm_kernel(const void* __restrict__ Asrc,
                                                   const ushort_t* __restrict__ Bp,
                                                   ushort_t* __restrict__ C, int M,
                                                   const float* __restrict__ scale,
                                                   const float* __restrict__ shift,
                                                   const float* __restrict__ a_src,
                                                   const float* __restrict__ a_dst,
                                                   float* __restrict__ as_,
                                                   float* __restrict__ ad_){
  gemm_body<K, NT, AMODE, ALPHA>(blockIdx.x, 0, NT * 16, 0, Asrc, Bp, C, M,
                                 scale, shift, a_src, a_dst, as_, ad_);
}

// role-split launch: blocks [0, GB*4) = GEMM1 split into 4 head-chunks (NT=4 each,
// low VGPR, high occupancy); blocks [GB*4, ..) = degree histogram.
// Histogram replica index (hb & 7) matches scatter's (e/256)&7 partition exactly.
__global__ __launch_bounds__(256) void hist_gemm1_kernel(int GB4, const int* __restrict__ ei,
                                                         int* __restrict__ deg8, int E, int N,
                                                         const float* __restrict__ x,
                                                         const ushort_t* __restrict__ W1p,
                                                         ushort_t* __restrict__ h1b,
                                                         const float* __restrict__ a1s,
                                                         const float* __restrict__ a1d,
                                                         float* __restrict__ as_,
                                                         float* __restrict__ ad_){
  int b = blockIdx.x;
  if(b < GB4){
    int bx = b >> 2, head = b & 3;
    gemm_body<128, 4, 0, 4>(bx, head * 4, 256, head, x, W1p, h1b, N,
                            nullptr, nullptr, a1s, a1d, as_, ad_);
  } else {
    int hb = b - GB4;
    int e = hb * 256 + threadIdx.x;
    if(e < E + N){
      int d = (e < E) ? ei[E + e] : (e - E);   // self loop for e >= E
      atomicAdd(&deg8[(size_t)(hb & 7) * N + d], 1);
    }
  }
}

// ---------------- CSR scan over 8 replicas ----------------
// Reads deg8[r][i], writes per-replica cursors back IN PLACE (deg8 becomes cur8),
// rowptr[i] = block-local INCLUSIVE prefix of node totals; last block scans partials.

__global__ __launch_bounds__(256) void scan1_kernel(int* __restrict__ deg8, int* __restrict__ rowptr,
                                                    int* __restrict__ partials,
                                                    unsigned* __restrict__ tick, int n){
  int t = threadIdx.x, lane = t & 63, wv = t >> 6;
  int base = blockIdx.x * 2048 + t * 8;
  int v[8]; int run = 0;
  #pragma unroll
  for(int k = 0; k < 8; k++){
    int i = base + k; int s = 0;
    if(i < n){
      #pragma unroll
      for(int r = 0; r < 8; r++) s += deg8[(size_t)r * n + i];
    }
    v[k] = s; run += s;
  }
  int sc = run;
  #pragma unroll
  for(int off = 1; off < 64; off <<= 1){
    int u = __shfl_up(sc, off);
    if(lane >= off) sc += u;
  }
  __shared__ int wtot[4], woff[4];
  __shared__ bool slast;
  if(lane == 63) wtot[wv] = sc;
  __syncthreads();
  if(t == 0){
    int a = 0;
    #pragma unroll
    for(int i = 0; i < 4; i++){ woff[i] = a; a += wtot[i]; }
    partials[blockIdx.x] = a;
  }
  __syncthreads();
  int excl = (sc - run) + woff[wv];
  #pragma unroll
  for(int k = 0; k < 8; k++){
    int i = base + k;
    if(i < n){
      int run2 = excl;
      #pragma unroll
      for(int r = 0; r < 8; r++){
        int tmp = deg8[(size_t)r * n + i];
        deg8[(size_t)r * n + i] = run2;      // replica-r cursor (block-local)
        run2 += tmp;
      }
      excl = run2;
      rowptr[i] = excl;                      // inclusive local prefix (segment end)
    }
  }
  if(t == 0){
    __threadfence();
    slast = (atomicAdd(tick, 1u) == (unsigned)(gridDim.x - 1));
  }
  __syncthreads();
  if(slast && t < 64){
    int nb = gridDim.x;
    int pv = (t < nb) ? atomicAdd(&partials[t], 0) : 0;   // coherent read
    int psc = pv;
    #pragma unroll
    for(int off = 1; off < 64; off <<= 1){
      int u = __shfl_up(psc, off);
      if(t >= off) psc += u;
    }
    if(t < nb) partials[t] = psc - pv;
  }
}

// scatter bumps cur8[blockIdx&7][d]; same (e/256)&7 replica partition as hist.
__global__ void scatter_kernel(const int* __restrict__ ei, int* __restrict__ cur8,
                               const int* __restrict__ part, int* __restrict__ col, int E, int N){
  int e = blockIdx.x * 256 + threadIdx.x;
  if(e >= E + N) return;
  int s, d;
  if(e < E){ s = ei[e]; d = ei[E + e]; } else { s = e - E; d = e - E; }
  int pos = atomicAdd(&cur8[(size_t)(blockIdx.x & 7) * N + d], 1) + part[d >> 11];
  col[pos] = s;
}

// ---------------- single-pass GAT aggregation (round-5 loop, packed-f32 accumulate) ----------------
// out = (sum w*h)/(sum w); logits tiny so no max-subtraction needed.
// H=4: 2 lane-groups of 32; 4 edges in flight via 4x unroll; no LDS, no atomics.

__global__ __launch_bounds__(256) void gat_agg4_kernel(const ushort_t* __restrict__ hfeat,
                                                       const float* __restrict__ as_,
                                                       const float* __restrict__ ad_,
                                                       const int* __restrict__ rowptr,
                                                       const int* __restrict__ part,
                                                       const int* __restrict__ col,
                                                       const float* __restrict__ bias,
                                                       ushort_t* __restrict__ out, int N){
  int wid = threadIdx.x >> 6, lane = threadIdx.x & 63;
  int n = blockIdx.x * 4 + wid;
  if(n > N - 1) n = N - 1;
  int start = n ? rowptr[n - 1] + part[(n - 1) >> 11] : 0;
  int end   = rowptr[n] + part[n >> 11];
  int g = lane >> 5, l = lane & 31, hidx = l >> 3;
  float adh = ad_[(size_t)n * 4 + hidx];
  float den = 0.f;
  f32x2 acc2[4] = {};
  auto body = [&](int j){
    int s = col[j];
    float w = __expf(lrelu(as_[(size_t)s * 4 + hidx] + adh));
    uint4 u = *reinterpret_cast<const uint4*>(hfeat + (size_t)s * 256 + 8 * l);
    den += w;
    acc2[0] += unpk2(u.x) * w;
    acc2[1] += unpk2(u.y) * w;
    acc2[2] += unpk2(u.z) * w;
    acc2[3] += unpk2(u.w) * w;
  };
  int j = start + g;
  for(; j + 6 < end; j += 8){ body(j); body(j + 2); body(j + 4); body(j + 6); }
  for(; j < end; j += 2) body(j);
  den += __shfl_xor(den, 32);
  #pragma unroll
  for(int k = 0; k < 4; k++){
    acc2[k].x += __shfl_xor(acc2[k].x, 32);
    acc2[k].y += __shfl_xor(acc2[k].y, 32);
  }
  float dinv = 1.f / (den + 1e-16f);
  int cbase = 8 * l + g * 4;
  f32x2 p0 = g ? acc2[2] : acc2[0];
  f32x2 p1 = g ? acc2[3] : acc2[1];
  ushort_t o0 = f2bf(p0.x * dinv + bias[cbase + 0]);
  ushort_t o1 = f2bf(p0.y * dinv + bias[cbase + 1]);
  ushort_t o2 = f2bf(p1.x * dinv + bias[cbase + 2]);
  ushort_t o3 = f2bf(p1.y * dinv + bias[cbase + 3]);
  uint2 pk; pk.x = o0 | ((unsigned)o1 << 16); pk.y = o2 | ((unsigned)o3 << 16);
  *reinterpret_cast<uint2*>(out + (size_t)n * 256 + cbase) = pk;
}

// H=1: 4 lane-groups of 16, uint2 gathers, round-5 loop, packed accumulate.

__global__ __launch_bounds__(256) void gat_agg1_kernel(const ushort_t* __restrict__ hfeat,
                                                       const float* __restrict__ as_,
                                                       const float* __restrict__ ad_,
                                                       const int* __restrict__ rowptr,
                                                       const int* __restrict__ part,
                                                       const int* __restrict__ col,
                                                       const float* __restrict__ bias,
                                                       ushort_t* __restrict__ out, int N){
  int wid = threadIdx.x >> 6, lane = threadIdx.x & 63;
  int n = blockIdx.x * 4 + wid;
  if(n > N - 1) n = N - 1;
  int start = n ? rowptr[n - 1] + part[(n - 1) >> 11] : 0;
  int end   = rowptr[n] + part[n >> 11];
  int g = lane >> 4, l = lane & 15;
  float adn = ad_[n];
  float den = 0.f;
  f32x2 acc2[2] = {};
  auto body = [&](int j){
    int s = col[j];
    float w = __expf(lrelu(as_[s] + adn));
    uint2 u = *reinterpret_cast<const uint2*>(hfeat + (size_t)s * 64 + 4 * l);
    den += w;
    acc2[0] += unpk2(u.x) * w;
    acc2[1] += unpk2(u.y) * w;
  };
  int j = start + g;
  for(; j + 4 < end; j += 8){ body(j); body(j + 4); }
  if(j < end) body(j);
  den += __shfl_xor(den, 16); den += __shfl_xor(den, 32);
  #pragma unroll
  for(int k = 0; k < 2; k++){
    acc2[k].x += __shfl_xor(acc2[k].x, 16); acc2[k].x += __shfl_xor(acc2[k].x, 32);
    acc2[k].y += __shfl_xor(acc2[k].y, 16); acc2[k].y += __shfl_xor(acc2[k].y, 32);
  }
  float dinv = 1.f / (den + 1e-16f);
  if(g == 0){
    ushort_t o0 = f2bf(acc2[0].x * dinv + bias[4 * l + 0]);
    ushort_t o1 = f2bf(acc2[0].y * dinv + bias[4 * l + 1]);
    ushort_t o2 = f2bf(acc2[1].x * dinv + bias[4 * l + 2]);
    ushort_t o3 = f2bf(acc2[1].y * dinv + bias[4 * l + 3]);
    uint2 pk; pk.x = o0 | ((unsigned)o1 << 16); pk.y = o2 | ((unsigned)o3 << 16);
    *reinterpret_cast<uint2*>(out + (size_t)n * 64 + 4 * l) = pk;
  }
}

// ---------------- column stats (vectorized uint4 = 8ch/thread) + last-block finalize ----------------
// 512 blocks only: grid-level atomic reduction stays cheap.

template<int C>
__global__ __launch_bounds__(256) void colstats_fin_kernel(const ushort_t* __restrict__ x, int N,
                                                           float* __restrict__ stats,
                                                           const float* __restrict__ gamma,
                                                           const float* __restrict__ beta,
                                                           float* __restrict__ scale,
                                                           float* __restrict__ shift,
                                                           unsigned* __restrict__ ticket, int nblk){
  constexpr int TPR = C / 8;           // threads per row
  constexpr int RPB = 256 / TPR;       // rows per block-iter
  int t = threadIdx.x;
  int c0 = (t % TPR) * 8, rg = t / TPR;
  float sum[8] = {}, sq[8] = {};
  for(int r = blockIdx.x * RPB + rg; r < N; r += gridDim.x * RPB){
    uint4 u = *reinterpret_cast<const uint4*>(x + (size_t)r * C + c0);
    float a, b;
    unpk(u.x, a, b); sum[0] += a; sq[0] += a * a; sum[1] += b; sq[1] += b * b;
    unpk(u.y, a, b); sum[2] += a; sq[2] += a * a; sum[3] += b; sq[3] += b * b;
    unpk(u.z, a, b); sum[4] += a; sq[4] += a * a; sum[5] += b; sq[5] += b * b;
    unpk(u.w, a, b); sum[6] += a; sq[6] += a * a; sum[7] += b; sq[7] += b * b;
  }
  __shared__ float red[2][256][8];     // 16 KB
  #pragma unroll
  for(int k = 0; k < 8; k++){ red[0][t][k] = sum[k]; red[1][t][k] = sq[k]; }
  __syncthreads();
  if(t < C){
    int tr = t >> 3, k = t & 7;
    float S = 0.f, Q = 0.f;
    for(int g2 = 0; g2 < RPB; g2++){
      S += red[0][g2 * TPR + tr][k];
      Q += red[1][g2 * TPR + tr][k];
    }
    atomicAdd(&stats[t], S);
    atomicAdd(&stats[C + t], Q);
  }
  __shared__ bool is_last;
  __syncthreads();
  if(t == 0){
    __threadfence();
    is_last = (atomicAdd(ticket, 1u) == (unsigned)(nblk - 1));
  }
  __syncthreads();
  if(is_last && t < C){
    float S = atomicAdd(&stats[t], 0.f);        // coherent read
    float Q = atomicAdd(&stats[C + t], 0.f);
    float invN = 1.f / (float)N;
    float mu = S * invN;
    float var = Q * invN - mu * mu;
    float rs = rsqrtf(var + EPS_BN);
    float scl = rs * gamma[t];
    scale[t] = scl;
    shift[t] = beta[t] - mu * scl;
  }
}

// ---------------- final BN (pure affine, vectorized 8ch/thread, fp32 out) ----------------

__global__ void bn3_kernel(const ushort_t* __restrict__ x, const float* __restrict__ scale,
                           const float* __restrict__ shift, float* __restrict__ y, long total8){
  long i = (long)blockIdx.x * 256 + threadIdx.x;
  if(i >= total8) return;
  long e0 = i * 8;
  int c0 = (int)(e0 & 127);
  uint4 u = *reinterpret_cast<const uint4*>(x + e0);
  float4 sc0 = *reinterpret_cast<const float4*>(scale + c0);
  float4 sc1 = *reinterpret_cast<const float4*>(scale + c0 + 4);
  float4 sh0 = *reinterpret_cast<const float4*>(shift + c0);
  float4 sh1 = *reinterpret_cast<const float4*>(shift + c0 + 4);
  float a, b;
  float4 o0, o1;
  unpk(u.x, a, b); o0.x = a * sc0.x + sh0.x; o0.y = b * sc0.y + sh0.y;
  unpk(u.y, a, b); o0.z = a * sc0.z + sh0.z; o0.w = b * sc0.w + sh0.w;
  unpk(u.z, a, b); o1.x = a * sc1.x + sh1.x; o1.y = b * sc1.y + sh1.y;
  unpk(u.w, a, b); o1.z = a * sc1.z + sh1.z; o1.w = b * sc1.w + sh1.w;
  *reinterpret_cast<float4*>(y + e0) = o0;
  *reinterpret_cast<float4*>(y + e0 + 4) = o1;
}

// ---------------- launch ----------------

extern "C" void kernel_launch(void* const* d_in, const int* in_sizes, int n_in,
                              void* d_out, int out_size, void* d_ws, size_t ws_size,
                              hipStream_t stream){
  const float* x   = (const float*)d_in[0];
  const int*   ei  = (const int*)  d_in[1];
  const float* W1  = (const float*)d_in[2];
  const float* a1s = (const float*)d_in[3];
  const float* a1d = (const float*)d_in[4];
  const float* b1  = (const float*)d_in[5];
  const float* W2  = (const float*)d_in[6];
  const float* a2s = (const float*)d_in[7];
  const float* a2d = (const float*)d_in[8];
  const float* b2  = (const float*)d_in[9];
  const float* Wp  = (const float*)d_in[10];
  const float* g1  = (const float*)d_in[12]; const float* be1 = (const float*)d_in[13];
  const float* g2  = (const float*)d_in[14]; const float* be2 = (const float*)d_in[15];
  const float* g3  = (const float*)d_in[16]; const float* be3 = (const float*)d_in[17];
  float* out = (float*)d_out;

  const int N  = in_sizes[0] / 128;
  const int E  = in_sizes[1] / 2;
  const int EP = E + N;
  const int Mpad = ((N + 63) / 64) * 64;
  const int NB = ceil_div(N, 2048);
  const int GB = Mpad / 64;
  const int HB = ceil_div(EP, 256);

  // ---- workspace carve ----
  char* p = (char*)d_ws;
  auto carve = [&](size_t bytes) -> char* {
    char* r = p; p += (bytes + 255) & ~(size_t)255; return r;
  };
  float* meta   = (float*)carve(2048 * 4);          // stats/scale/shift/tickets (zeroed)
  int*   deg8   = (int*)carve((size_t)8 * N * 4);   // contiguous after meta; becomes cur8
  int*   rowptr = (int*)carve((size_t)(N + 1) * 4);
  int*   col    = (int*)carve((size_t)EP * 4);
  int*   part   = (int*)carve(64 * 4);
  float* as_    = (float*)carve((size_t)N * 4 * 4);
  float* ad_    = (float*)carve((size_t)N * 4 * 4);
  ushort_t* W1p = (ushort_t*)carve((size_t)128 * 256 * 2);
  ushort_t* W2p = (ushort_t*)carve((size_t)256 * 64 * 2);
  ushort_t* W3p = (ushort_t*)carve((size_t)64 * 128 * 2);
  ushort_t* h1b   = (ushort_t*)carve((size_t)Mpad * 256 * 2);
  ushort_t* out1b = (ushort_t*)carve((size_t)Mpad * 256 * 2);
  ushort_t* h2b   = (ushort_t*)carve((size_t)Mpad * 64 * 2);
  ushort_t* out2b = (ushort_t*)carve((size_t)Mpad * 64 * 2);
  ushort_t* h3b   = (ushort_t*)carve((size_t)Mpad * 128 * 2);

  float* stats1 = meta;        float* scale1 = meta + 512;  float* shift1 = meta + 768;
  float* stats2 = meta + 1024; float* scale2 = meta + 1152; float* shift2 = meta + 1216;
  float* stats3 = meta + 1280; float* scale3 = meta + 1536; float* shift3 = meta + 1664;
  unsigned* tick = (unsigned*)(meta + 1792);        // [0..2]=colstats, [3]=scan

  const int ZT = 2048 + 8 * N;
  // 1) zero meta+deg8 + pack all weights (role-split)
  init_kernel<<<28 + ceil_div(ZT, 256), 256, 0, stream>>>((unsigned*)meta, ZT,
                                                          W1, W2, Wp, W1p, W2p, W3p);
  // 2) GEMM1 (4 head-chunks, NT=4, fused f2bf + alpha) + replicated histogram (role-split)
  hist_gemm1_kernel<<<GB * 4 + HB, 256, 0, stream>>>(GB * 4, ei, deg8, E, N, x, W1p, h1b,
                                                     a1s, a1d, as_, ad_);
  // 3) CSR scan (8-replica sum; deg8 -> cur8 in place; rowptr inclusive-local)
  scan1_kernel<<<NB, 256, 0, stream>>>(deg8, rowptr, part, tick + 3, N);
  // 4) scatter (replica-partitioned atomics)
  scatter_kernel<<<HB, 256, 0, stream>>>(ei, deg8, part, col, E, N);
  // 5) layer-1 aggregation
  gat_agg4_kernel<<<ceil_div(N, 4), 256, 0, stream>>>(h1b, as_, ad_, rowptr, part, col, b1, out1b, N);
  colstats_fin_kernel<256><<<512, 256, 0, stream>>>(out1b, N, stats1, g1, be1, scale1, shift1, tick + 0, 512);
  // 6) GEMM2 (fused BN1+ELU on A + alpha)
  gemm_kernel<256, 4, 1, 1><<<GB, 256, 0, stream>>>(out1b, W2p, h2b, N, scale1, shift1, a2s, a2d, as_, ad_);
  // 7) layer-2 aggregation
  gat_agg1_kernel<<<ceil_div(N, 4), 256, 0, stream>>>(h2b, as_, ad_, rowptr, part, col, b2, out2b, N);
  colstats_fin_kernel<64><<<512, 256, 0, stream>>>(out2b, N, stats2, g2, be2, scale2, shift2, tick + 1, 512);
  // 8) projection GEMM (fused BN2+ELU on A)
  gemm_kernel<64, 8, 1, 0><<<GB, 256, 0, stream>>>(out2b, W3p, h3b, N, scale2, shift2, nullptr, nullptr, nullptr, nullptr);
  colstats_fin_kernel<128><<<512, 256, 0, stream>>>(h3b, N, stats3, g3, be3, scale3, shift3, tick + 2, 512);
  // 9) final BN
  bn3_kernel<<<ceil_div(N * 16, 256), 256, 0, stream>>>(h3b, scale3, shift3, out, (long)N * 16);
}